// Round 1
// baseline (489.908 us; speedup 1.0000x reference)
//
#include <hip/hip_runtime.h>
#include <hip/hip_bf16.h>

// Problem constants (fixed by reference setup_inputs)
#define NNODES 50000
#define NEDGES 800000
#define DIN    512
#define FOUT   256

typedef __attribute__((ext_vector_type(8))) short short8;
typedef __attribute__((ext_vector_type(4))) float f32x4;
typedef __attribute__((ext_vector_type(4))) unsigned int u32x4;
typedef __attribute__((ext_vector_type(4))) unsigned short usv4;

static __device__ __forceinline__ unsigned short f2bf(float f) {
    unsigned int u = __float_as_uint(f);
    u += 0x7FFF + ((u >> 16) & 1);   // round-to-nearest-even
    return (unsigned short)(u >> 16);
}
static __device__ __forceinline__ float bf2f(unsigned short h) {
    return __uint_as_float(((unsigned int)h) << 16);
}

// ---------------- W^T convert: W[512][256] f32 -> Wt[256][512] bf16 ----------
__global__ void wt_convert(const float* __restrict__ W, unsigned short* __restrict__ Wt) {
    int o = blockIdx.x * 256 + threadIdx.x;      // 131072 total
    int n = o >> 9, k = o & 511;
    Wt[o] = f2bf(W[k * FOUT + n]);
}

// ---------------- CSR build -------------------------------------------------
__global__ void hist_kernel(const int* __restrict__ row, int* __restrict__ cnt) {
    int e = blockIdx.x * 256 + threadIdx.x;
    if (e < NEDGES) atomicAdd(&cnt[row[e]], 1);
}

__global__ void scan_partial(const int* __restrict__ cnt, int* __restrict__ partial) {
    __shared__ int sm[256];
    int i = blockIdx.x * 256 + threadIdx.x;
    int v = (i < NNODES) ? cnt[i] : 0;
    sm[threadIdx.x] = v; __syncthreads();
    for (int s = 128; s > 0; s >>= 1) {
        if (threadIdx.x < s) sm[threadIdx.x] += sm[threadIdx.x + s];
        __syncthreads();
    }
    if (threadIdx.x == 0) partial[blockIdx.x] = sm[0];
}

__global__ void scan_exclusive_small(int* __restrict__ partial, int nb) {
    __shared__ int sm[256];
    int t = threadIdx.x;
    int v = (t < nb) ? partial[t] : 0;
    sm[t] = v; __syncthreads();
    for (int off = 1; off < 256; off <<= 1) {
        int add = (t >= off) ? sm[t - off] : 0;
        __syncthreads();
        sm[t] += add;
        __syncthreads();
    }
    if (t < nb) partial[t] = sm[t] - v;   // exclusive
}

// Writes row_start AND initializes the scatter cursor to the same value
// (cursor aliases cnt: each thread reads cnt[i] first, writes it last — safe).
__global__ void scan_write(const int* __restrict__ cnt, const int* __restrict__ partial,
                           int* __restrict__ row_start, int* __restrict__ cursor) {
    __shared__ int sm[256];
    int t = threadIdx.x;
    int i = blockIdx.x * 256 + t;
    int v = (i < NNODES) ? cnt[i] : 0;
    sm[t] = v; __syncthreads();
    for (int off = 1; off < 256; off <<= 1) {
        int add = (t >= off) ? sm[t - off] : 0;
        __syncthreads();
        sm[t] += add;
        __syncthreads();
    }
    if (i < NNODES) {
        int rs = partial[blockIdx.x] + sm[t] - v;
        row_start[i] = rs;
        cursor[i] = rs;          // absolute cursor for scatter
    }
    if (i == 0) row_start[NNODES] = NEDGES;
}

// scatter: cursor[r] pre-initialized to row_start[r] -> atomicAdd gives the
// absolute CSR slot directly (no row_start read per edge).
__global__ void scatter_kernel(const int* __restrict__ row, const int* __restrict__ col,
                               const float* __restrict__ val,
                               int* __restrict__ cursor, unsigned int* __restrict__ cv) {
    int e = blockIdx.x * 256 + threadIdx.x;
    if (e < NEDGES) {
        int r = row[e];
        int pos = atomicAdd(&cursor[r], 1);
        unsigned int vb = f2bf(val[e]);
        cv[pos] = (vb << 16) | (unsigned int)col[e];
    }
}

// ---------------- GEMM: S[m][512] = [X@W (ori) | X@W (aug)] bf16 ------------
// block tile 128(m) x 256(n=all of F), BK=32, 512 threads = 8 waves (2x4),
// wave tile 64x64 (4x4 MFMA 16x16x32). X fp32 read exactly ONCE per branch
// (nontemporal: zero reuse, keep L2/L3 for S). Double-buffered LDS, ONE
// barrier per K-step, T14 split: issue loads -> MFMA (loads in flight) ->
// cvt+ds_write -> barrier. Buffer index is a compile-time literal so the
// compiler can disambiguate As[0]/As[1] DS accesses.
// LDS rows padded to 40 shorts (80B): ds_read_b128 2-way bank alias = free.
__global__ __launch_bounds__(512, 2)
void gemm_kernel(const float* __restrict__ Xo, const float* __restrict__ Xa,
                 const unsigned short* __restrict__ Wt,
                 unsigned short* __restrict__ S) {
    __shared__ __align__(16) unsigned short As[2][128][40];
    __shared__ __align__(16) unsigned short Bs[2][256][40];
    const int tid = threadIdx.x;
    const int branch = blockIdx.z;
    const float* __restrict__ X = branch ? Xa : Xo;
    const int boff = branch * 256;
    const int m_base = blockIdx.x * 128;
    const int lane = tid & 63, wave = tid >> 6;
    const int wm = (wave >> 2) * 64, wn = (wave & 3) * 64;
    const int quad = lane >> 4, r16 = lane & 15;

    f32x4 acc[4][4] = {};

    // staging geometry (512 threads)
    const int colf  = (tid & 7) * 4;   // A: float4 column within 32-k tile
    const int rbase = tid >> 3;        // A: row 0..63 (2 passes)
    const int kseg  = (tid & 3) * 8;   // B: 8-bf16 segment
    const int nrow  = tid >> 2;        // B: n row 0..127 (2 passes)

    const int gm0 = m_base + rbase;
    const int gm1 = m_base + 64 + rbase;
    const bool va0 = gm0 < NNODES, va1 = gm1 < NNODES;
    const float* pA0 = &X[(long)gm0 * DIN + colf];
    const float* pA1 = &X[(long)gm1 * DIN + colf];
    const unsigned short* pB0 = &Wt[(long)nrow * DIN + kseg];
    const unsigned short* pB1 = &Wt[(long)(128 + nrow) * DIN + kseg];

    f32x4 fa0, fa1; u32x4 ub0, ub1;

#define GEMM_LOAD(K0)                                                          \
    do {                                                                       \
        fa0 = va0 ? __builtin_nontemporal_load((const f32x4*)(pA0 + (K0)))     \
                  : (f32x4)0.f;                                                \
        fa1 = va1 ? __builtin_nontemporal_load((const f32x4*)(pA1 + (K0)))     \
                  : (f32x4)0.f;                                                \
        ub0 = *(const u32x4*)(pB0 + (K0));                                     \
        ub1 = *(const u32x4*)(pB1 + (K0));                                     \
    } while (0)

#define GEMM_WRITE(B)                                                          \
    do {                                                                       \
        usv4 h0; h0.x = f2bf(fa0[0]); h0.y = f2bf(fa0[1]);                     \
        h0.z = f2bf(fa0[2]); h0.w = f2bf(fa0[3]);                              \
        *(usv4*)&As[B][rbase][colf] = h0;                                      \
        usv4 h1; h1.x = f2bf(fa1[0]); h1.y = f2bf(fa1[1]);                     \
        h1.z = f2bf(fa1[2]); h1.w = f2bf(fa1[3]);                              \
        *(usv4*)&As[B][64 + rbase][colf] = h1;                                 \
        *(u32x4*)&Bs[B][nrow][kseg] = ub0;                                     \
        *(u32x4*)&Bs[B][128 + nrow][kseg] = ub1;                               \
    } while (0)

#define GEMM_COMPUTE(B)                                                        \
    do {                                                                       \
        short8 a_frag[4], b_frag[4];                                           \
        _Pragma("unroll")                                                      \
        for (int mi = 0; mi < 4; mi++)                                         \
            a_frag[mi] = *(const short8*)&As[B][wm + mi * 16 + r16][quad * 8]; \
        _Pragma("unroll")                                                      \
        for (int ni = 0; ni < 4; ni++)                                         \
            b_frag[ni] = *(const short8*)&Bs[B][wn + ni * 16 + r16][quad * 8]; \
        _Pragma("unroll")                                                      \
        for (int mi = 0; mi < 4; mi++)                                         \
            _Pragma("unroll")                                                  \
            for (int ni = 0; ni < 4; ni++)                                     \
                acc[mi][ni] = __builtin_amdgcn_mfma_f32_16x16x32_bf16(         \
                    a_frag[mi], b_frag[ni], acc[mi][ni], 0, 0, 0);             \
    } while (0)

    // prologue: stage k-tile 0 into buf0
    GEMM_LOAD(0);
    GEMM_WRITE(0);
    __syncthreads();

    for (int k0 = 0; k0 < DIN; k0 += 64) {
        // ---- half-step A: compute buf0 (k0), stage buf1 (k0+32) ----
        GEMM_LOAD(k0 + 32);          // issue loads (in flight under MFMA)
        GEMM_COMPUTE(0);
        GEMM_WRITE(1);               // vmcnt wait lands here, after MFMA
        __syncthreads();
        // ---- half-step B: compute buf1 (k0+32), stage buf0 (k0+64) ----
        if (k0 + 64 < DIN) GEMM_LOAD(k0 + 64);
        GEMM_COMPUTE(1);
        if (k0 + 64 < DIN) GEMM_WRITE(0);
        __syncthreads();
    }

#undef GEMM_LOAD
#undef GEMM_WRITE
#undef GEMM_COMPUTE

    // epilogue: bf16 support, interleaved [m][ori 0..255 | aug 256..511]
    // C/D map: col(n)=lane&15, row(m)=quad*4+reg
    #pragma unroll
    for (int mi = 0; mi < 4; mi++) {
        #pragma unroll
        for (int rr = 0; rr < 4; rr++) {
            int m = m_base + wm + mi * 16 + quad * 4 + rr;
            if (m < NNODES) {
                #pragma unroll
                for (int ni = 0; ni < 4; ni++) {
                    int n = wn + ni * 16 + r16;
                    S[(long)m * 512 + boff + n] = f2bf(acc[mi][ni][rr]);
                }
            }
        }
    }
}

// ---------------- Aggregation: one wave per node, 4-edge unroll -------------
// cv read-once (nontemporal), out write-once (nontemporal) -> keep L2/L3
// capacity for the 819 MB logical gather of S (51.2 MB, L3-resident).
__global__ __launch_bounds__(256)
void aggregate_kernel(const int* __restrict__ row_start,
                      const unsigned int* __restrict__ cv,
                      const unsigned short* __restrict__ S,
                      const float* __restrict__ bias, float* __restrict__ out) {
    int node = blockIdx.x * 4 + (threadIdx.x >> 6);
    int lane = threadIdx.x & 63;
    if (node >= NNODES) return;
    int s = row_start[node], e = row_start[node + 1];
    float ao0 = 0.f, ao1 = 0.f, ao2 = 0.f, ao3 = 0.f;
    float aa0 = 0.f, aa1 = 0.f, aa2 = 0.f, aa3 = 0.f;
    const int lo = lane * 4;

    int idx = s;
    for (; idx + 4 <= e; idx += 4) {
        unsigned int w0 = __builtin_nontemporal_load(&cv[idx]);
        unsigned int w1 = __builtin_nontemporal_load(&cv[idx + 1]);
        unsigned int w2 = __builtin_nontemporal_load(&cv[idx + 2]);
        unsigned int w3 = __builtin_nontemporal_load(&cv[idx + 3]);
        const unsigned short* p0 = &S[(long)(w0 & 0xFFFFu) * 512 + lo];
        const unsigned short* p1 = &S[(long)(w1 & 0xFFFFu) * 512 + lo];
        const unsigned short* p2 = &S[(long)(w2 & 0xFFFFu) * 512 + lo];
        const unsigned short* p3 = &S[(long)(w3 & 0xFFFFu) * 512 + lo];
        usv4 po0 = *(const usv4*)p0;       usv4 pa0 = *(const usv4*)(p0 + 256);
        usv4 po1 = *(const usv4*)p1;       usv4 pa1 = *(const usv4*)(p1 + 256);
        usv4 po2 = *(const usv4*)p2;       usv4 pa2 = *(const usv4*)(p2 + 256);
        usv4 po3 = *(const usv4*)p3;       usv4 pa3 = *(const usv4*)(p3 + 256);
        float v0 = bf2f((unsigned short)(w0 >> 16));
        float v1 = bf2f((unsigned short)(w1 >> 16));
        float v2 = bf2f((unsigned short)(w2 >> 16));
        float v3 = bf2f((unsigned short)(w3 >> 16));
        ao0 += v0 * bf2f(po0.x); ao1 += v0 * bf2f(po0.y); ao2 += v0 * bf2f(po0.z); ao3 += v0 * bf2f(po0.w);
        aa0 += v0 * bf2f(pa0.x); aa1 += v0 * bf2f(pa0.y); aa2 += v0 * bf2f(pa0.z); aa3 += v0 * bf2f(pa0.w);
        ao0 += v1 * bf2f(po1.x); ao1 += v1 * bf2f(po1.y); ao2 += v1 * bf2f(po1.z); ao3 += v1 * bf2f(po1.w);
        aa0 += v1 * bf2f(pa1.x); aa1 += v1 * bf2f(pa1.y); aa2 += v1 * bf2f(pa1.z); aa3 += v1 * bf2f(pa1.w);
        ao0 += v2 * bf2f(po2.x); ao1 += v2 * bf2f(po2.y); ao2 += v2 * bf2f(po2.z); ao3 += v2 * bf2f(po2.w);
        aa0 += v2 * bf2f(pa2.x); aa1 += v2 * bf2f(pa2.y); aa2 += v2 * bf2f(pa2.z); aa3 += v2 * bf2f(pa2.w);
        ao0 += v3 * bf2f(po3.x); ao1 += v3 * bf2f(po3.y); ao2 += v3 * bf2f(po3.z); ao3 += v3 * bf2f(po3.w);
        aa0 += v3 * bf2f(pa3.x); aa1 += v3 * bf2f(pa3.y); aa2 += v3 * bf2f(pa3.z); aa3 += v3 * bf2f(pa3.w);
    }
    for (; idx < e; idx++) {
        unsigned int w = __builtin_nontemporal_load(&cv[idx]);
        const unsigned short* p = &S[(long)(w & 0xFFFFu) * 512 + lo];
        usv4 po = *(const usv4*)p;
        usv4 pa = *(const usv4*)(p + 256);
        float v = bf2f((unsigned short)(w >> 16));
        ao0 += v * bf2f(po.x); ao1 += v * bf2f(po.y); ao2 += v * bf2f(po.z); ao3 += v * bf2f(po.w);
        aa0 += v * bf2f(pa.x); aa1 += v * bf2f(pa.y); aa2 += v * bf2f(pa.z); aa3 += v * bf2f(pa.w);
    }

    f32x4 b = *(const f32x4*)&bias[lo];
    long o = (long)node * FOUT + lo;
    f32x4 ro, ra;
    ro[0] = fmaxf(ao0 + b[0], 0.f); ro[1] = fmaxf(ao1 + b[1], 0.f);
    ro[2] = fmaxf(ao2 + b[2], 0.f); ro[3] = fmaxf(ao3 + b[3], 0.f);
    ra[0] = fmaxf(aa0 + b[0], 0.f); ra[1] = fmaxf(aa1 + b[1], 0.f);
    ra[2] = fmaxf(aa2 + b[2], 0.f); ra[3] = fmaxf(aa3 + b[3], 0.f);
    __builtin_nontemporal_store(ro, (f32x4*)&out[o]);
    __builtin_nontemporal_store(ra, (f32x4*)&out[(long)NNODES * FOUT + o]);
}

// ---------------- launch ----------------------------------------------------
extern "C" void kernel_launch(void* const* d_in, const int* in_sizes, int n_in,
                              void* d_out, int out_size, void* d_ws, size_t ws_size,
                              hipStream_t stream) {
    const float* Xo   = (const float*)d_in[0];
    const float* Xa   = (const float*)d_in[1];
    const int*   erow = (const int*)d_in[2];
    const int*   ecol = (const int*)d_in[3];
    const float* eval_= (const float*)d_in[4];
    const float* W    = (const float*)d_in[5];
    const float* bias = (const float*)d_in[6];
    float* out = (float*)d_out;

    char* ws = (char*)d_ws;
    // workspace layout (~55.06 MB total)
    unsigned short* S         = (unsigned short*)(ws);                 // 51,200,000 B
    unsigned short* Wt        = (unsigned short*)(ws + 51200000);      //    262,144 B
    int*            cnt       = (int*)(ws + 51462144);                 //    200,000 B (hist, then cursor)
    int*            row_start = (int*)(ws + 51662144);                 //    200,064 B (50001 ints)
    int*            partial   = (int*)(ws + 51862208);                 //      1,024 B
    unsigned int*   cv        = (unsigned int*)(ws + 51863232);        //  3,200,000 B

    (void)in_sizes; (void)n_in; (void)out_size; (void)ws_size;

    hipMemsetAsync(cnt, 0, 200000, stream);
    wt_convert<<<512, 256, 0, stream>>>(W, Wt);
    hist_kernel<<<3125, 256, 0, stream>>>(erow, cnt);
    scan_partial<<<196, 256, 0, stream>>>(cnt, partial);
    scan_exclusive_small<<<1, 256, 0, stream>>>(partial, 196);
    scan_write<<<196, 256, 0, stream>>>(cnt, partial, row_start, cnt);
    scatter_kernel<<<3125, 256, 0, stream>>>(erow, ecol, eval_, cnt, cv);

    dim3 gg(391, 1, 2);
    gemm_kernel<<<gg, 512, 0, stream>>>(Xo, Xa, Wt, S);

    aggregate_kernel<<<12500, 256, 0, stream>>>(row_start, cv, S, bias, out);
}

// Round 2
// 487.023 us; speedup vs baseline: 1.0059x; 1.0059x over previous
//
#include <hip/hip_runtime.h>
#include <hip/hip_bf16.h>

// Problem constants (fixed by reference setup_inputs)
#define NNODES 50000
#define NEDGES 800000
#define DIN    512
#define FOUT   256

typedef __attribute__((ext_vector_type(8))) short short8;
typedef __attribute__((ext_vector_type(4))) float f32x4;
typedef __attribute__((ext_vector_type(4))) unsigned int u32x4;
typedef __attribute__((ext_vector_type(4))) unsigned short usv4;
typedef __attribute__((ext_vector_type(8))) unsigned short usv8;

static __device__ __forceinline__ unsigned short f2bf(float f) {
    unsigned int u = __float_as_uint(f);
    u += 0x7FFF + ((u >> 16) & 1);   // round-to-nearest-even
    return (unsigned short)(u >> 16);
}
static __device__ __forceinline__ float bf2f(unsigned short h) {
    return __uint_as_float(((unsigned int)h) << 16);
}

// ---------------- prep: W^T convert (blocks 0..511) + edge hist (512..) -----
__global__ void prep_kernel(const float* __restrict__ W, unsigned short* __restrict__ Wt,
                            const int* __restrict__ row, int* __restrict__ cnt) {
    int b = blockIdx.x;
    if (b < 512) {
        int o = b * 256 + threadIdx.x;           // 131072 total
        int n = o >> 9, k = o & 511;
        Wt[o] = f2bf(W[k * FOUT + n]);
    } else {
        int e = (b - 512) * 256 + threadIdx.x;
        if (e < NEDGES) atomicAdd(&cnt[row[e]], 1);
    }
}

// ---------------- CSR scan --------------------------------------------------
__global__ void scan_partial(const int* __restrict__ cnt, int* __restrict__ partial) {
    __shared__ int sm[256];
    int i = blockIdx.x * 256 + threadIdx.x;
    int v = (i < NNODES) ? cnt[i] : 0;
    sm[threadIdx.x] = v; __syncthreads();
    for (int s = 128; s > 0; s >>= 1) {
        if (threadIdx.x < s) sm[threadIdx.x] += sm[threadIdx.x + s];
        __syncthreads();
    }
    if (threadIdx.x == 0) partial[blockIdx.x] = sm[0];
}

__global__ void scan_exclusive_small(int* __restrict__ partial, int nb) {
    __shared__ int sm[256];
    int t = threadIdx.x;
    int v = (t < nb) ? partial[t] : 0;
    sm[t] = v; __syncthreads();
    for (int off = 1; off < 256; off <<= 1) {
        int add = (t >= off) ? sm[t - off] : 0;
        __syncthreads();
        sm[t] += add;
        __syncthreads();
    }
    if (t < nb) partial[t] = sm[t] - v;   // exclusive
}

// Writes row_start AND initializes the scatter cursor to the same value
// (cursor aliases cnt: each thread reads cnt[i] first, writes it last — safe).
__global__ void scan_write(const int* __restrict__ cnt, const int* __restrict__ partial,
                           int* __restrict__ row_start, int* __restrict__ cursor) {
    __shared__ int sm[256];
    int t = threadIdx.x;
    int i = blockIdx.x * 256 + t;
    int v = (i < NNODES) ? cnt[i] : 0;
    sm[t] = v; __syncthreads();
    for (int off = 1; off < 256; off <<= 1) {
        int add = (t >= off) ? sm[t - off] : 0;
        __syncthreads();
        sm[t] += add;
        __syncthreads();
    }
    if (i < NNODES) {
        int rs = partial[blockIdx.x] + sm[t] - v;
        row_start[i] = rs;
        cursor[i] = rs;          // absolute cursor for scatter
    }
    if (i == 0) row_start[NNODES] = NEDGES;
}

// scatter: cursor[r] pre-initialized to row_start[r] -> atomicAdd gives the
// absolute CSR slot directly (no row_start read per edge).
__global__ void scatter_kernel(const int* __restrict__ row, const int* __restrict__ col,
                               const float* __restrict__ val,
                               int* __restrict__ cursor, unsigned int* __restrict__ cv) {
    int e = blockIdx.x * 256 + threadIdx.x;
    if (e < NEDGES) {
        int r = row[e];
        int pos = atomicAdd(&cursor[r], 1);
        unsigned int vb = f2bf(val[e]);
        cv[pos] = (vb << 16) | (unsigned int)col[e];
    }
}

// ---------------- GEMM: S[m][512] = [X@W (ori) | X@W (aug)] bf16 ------------
// block tile 128(m) x 256(n=all of F), BK=32, 512 threads = 8 waves (2x4),
// wave tile 64x64 (4x4 MFMA 16x16x32). X fp32 read exactly ONCE per branch
// (nontemporal: zero reuse, keep L2/L3 for S). Double-buffered LDS, ONE
// barrier per K-step, T14 split: issue loads -> MFMA (loads in flight) ->
// cvt+ds_write -> barrier.
__global__ __launch_bounds__(512, 2)
void gemm_kernel(const float* __restrict__ Xo, const float* __restrict__ Xa,
                 const unsigned short* __restrict__ Wt,
                 unsigned short* __restrict__ S) {
    __shared__ __align__(16) unsigned short As[2][128][40];
    __shared__ __align__(16) unsigned short Bs[2][256][40];
    const int tid = threadIdx.x;
    const int branch = blockIdx.z;
    const float* __restrict__ X = branch ? Xa : Xo;
    const int boff = branch * 256;
    const int m_base = blockIdx.x * 128;
    const int lane = tid & 63, wave = tid >> 6;
    const int wm = (wave >> 2) * 64, wn = (wave & 3) * 64;
    const int quad = lane >> 4, r16 = lane & 15;

    f32x4 acc[4][4] = {};

    // staging geometry (512 threads)
    const int colf  = (tid & 7) * 4;   // A: float4 column within 32-k tile
    const int rbase = tid >> 3;        // A: row 0..63 (2 passes)
    const int kseg  = (tid & 3) * 8;   // B: 8-bf16 segment
    const int nrow  = tid >> 2;        // B: n row 0..127 (2 passes)

    const int gm0 = m_base + rbase;
    const int gm1 = m_base + 64 + rbase;
    const bool va0 = gm0 < NNODES, va1 = gm1 < NNODES;
    const float* pA0 = &X[(long)gm0 * DIN + colf];
    const float* pA1 = &X[(long)gm1 * DIN + colf];
    const unsigned short* pB0 = &Wt[(long)nrow * DIN + kseg];
    const unsigned short* pB1 = &Wt[(long)(128 + nrow) * DIN + kseg];

    f32x4 fa0, fa1; u32x4 ub0, ub1;

#define GEMM_LOAD(K0)                                                          \
    do {                                                                       \
        fa0 = va0 ? __builtin_nontemporal_load((const f32x4*)(pA0 + (K0)))     \
                  : (f32x4)0.f;                                                \
        fa1 = va1 ? __builtin_nontemporal_load((const f32x4*)(pA1 + (K0)))     \
                  : (f32x4)0.f;                                                \
        ub0 = *(const u32x4*)(pB0 + (K0));                                     \
        ub1 = *(const u32x4*)(pB1 + (K0));                                     \
    } while (0)

#define GEMM_WRITE(B)                                                          \
    do {                                                                       \
        usv4 h0; h0.x = f2bf(fa0[0]); h0.y = f2bf(fa0[1]);                     \
        h0.z = f2bf(fa0[2]); h0.w = f2bf(fa0[3]);                              \
        *(usv4*)&As[B][rbase][colf] = h0;                                      \
        usv4 h1; h1.x = f2bf(fa1[0]); h1.y = f2bf(fa1[1]);                     \
        h1.z = f2bf(fa1[2]); h1.w = f2bf(fa1[3]);                              \
        *(usv4*)&As[B][64 + rbase][colf] = h1;                                 \
        *(u32x4*)&Bs[B][nrow][kseg] = ub0;                                     \
        *(u32x4*)&Bs[B][128 + nrow][kseg] = ub1;                               \
    } while (0)

#define GEMM_COMPUTE(B)                                                        \
    do {                                                                       \
        short8 a_frag[4], b_frag[4];                                           \
        _Pragma("unroll")                                                      \
        for (int mi = 0; mi < 4; mi++)                                         \
            a_frag[mi] = *(const short8*)&As[B][wm + mi * 16 + r16][quad * 8]; \
        _Pragma("unroll")                                                      \
        for (int ni = 0; ni < 4; ni++)                                         \
            b_frag[ni] = *(const short8*)&Bs[B][wn + ni * 16 + r16][quad * 8]; \
        _Pragma("unroll")                                                      \
        for (int mi = 0; mi < 4; mi++)                                         \
            _Pragma("unroll")                                                  \
            for (int ni = 0; ni < 4; ni++)                                     \
                acc[mi][ni] = __builtin_amdgcn_mfma_f32_16x16x32_bf16(         \
                    a_frag[mi], b_frag[ni], acc[mi][ni], 0, 0, 0);             \
    } while (0)

    // prologue: stage k-tile 0 into buf0
    GEMM_LOAD(0);
    GEMM_WRITE(0);
    __syncthreads();

    for (int k0 = 0; k0 < DIN; k0 += 64) {
        // ---- half-step A: compute buf0 (k0), stage buf1 (k0+32) ----
        GEMM_LOAD(k0 + 32);          // issue loads (in flight under MFMA)
        GEMM_COMPUTE(0);
        GEMM_WRITE(1);               // vmcnt wait lands here, after MFMA
        __syncthreads();
        // ---- half-step B: compute buf1 (k0+32), stage buf0 (k0+64) ----
        if (k0 + 64 < DIN) GEMM_LOAD(k0 + 64);
        GEMM_COMPUTE(1);
        if (k0 + 64 < DIN) GEMM_WRITE(0);
        __syncthreads();
    }

#undef GEMM_LOAD
#undef GEMM_WRITE
#undef GEMM_COMPUTE

    // epilogue: bf16 support, interleaved [m][ori 0..255 | aug 256..511]
    // C/D map: col(n)=lane&15, row(m)=quad*4+reg. Plain (cached) stores: S is
    // the aggregate gather's working set, keep it in L2/L3.
    #pragma unroll
    for (int mi = 0; mi < 4; mi++) {
        #pragma unroll
        for (int rr = 0; rr < 4; rr++) {
            int m = m_base + wm + mi * 16 + quad * 4 + rr;
            if (m < NNODES) {
                #pragma unroll
                for (int ni = 0; ni < 4; ni++) {
                    int n = wn + ni * 16 + r16;
                    S[(long)m * 512 + boff + n] = f2bf(acc[mi][ni][rr]);
                }
            }
        }
    }
}

// ---------------- Aggregation: one wave per node ----------------------------
// Lane l owns 8 features of ONE branch (half = l>>5, f8 = (l&31)*8):
// one 16-B dwordx4 gather per lane per edge (was 2x 8-B). 4-edge groups with
// a 2-deep A/B software pipeline: group g+1's cv + S loads issue BEFORE
// group g's FMAs, so the L2/L3 round-trip overlaps the math (T14 pattern).
__global__ __launch_bounds__(256)
void aggregate_kernel(const int* __restrict__ row_start,
                      const unsigned int* __restrict__ cv,
                      const unsigned short* __restrict__ S,
                      const float* __restrict__ bias, float* __restrict__ out) {
    int node = blockIdx.x * 4 + (threadIdx.x >> 6);
    int lane = threadIdx.x & 63;
    if (node >= NNODES) return;
    int s = row_start[node], e = row_start[node + 1];
    const int f8 = (lane & 31) * 8;
    const long soff = (long)(lane >> 5) * 256 + f8;   // branch half + feature base
    float a0 = 0.f, a1 = 0.f, a2 = 0.f, a3 = 0.f;
    float a4 = 0.f, a5 = 0.f, a6 = 0.f, a7 = 0.f;

#define LOADG(C0, C1, C2, C3, Q0, Q1, Q2, Q3, I)                               \
    do {                                                                       \
        C0 = __builtin_nontemporal_load(&cv[(I)]);                             \
        C1 = __builtin_nontemporal_load(&cv[(I) + 1]);                         \
        C2 = __builtin_nontemporal_load(&cv[(I) + 2]);                         \
        C3 = __builtin_nontemporal_load(&cv[(I) + 3]);                         \
        Q0 = *(const usv8*)&S[(long)(C0 & 0xFFFFu) * 512 + soff];              \
        Q1 = *(const usv8*)&S[(long)(C1 & 0xFFFFu) * 512 + soff];              \
        Q2 = *(const usv8*)&S[(long)(C2 & 0xFFFFu) * 512 + soff];              \
        Q3 = *(const usv8*)&S[(long)(C3 & 0xFFFFu) * 512 + soff];              \
    } while (0)

#define EDGE_FMA(Cw, Q)                                                        \
    do {                                                                       \
        float v = bf2f((unsigned short)((Cw) >> 16));                          \
        a0 = fmaf(v, bf2f((Q)[0]), a0); a1 = fmaf(v, bf2f((Q)[1]), a1);        \
        a2 = fmaf(v, bf2f((Q)[2]), a2); a3 = fmaf(v, bf2f((Q)[3]), a3);        \
        a4 = fmaf(v, bf2f((Q)[4]), a4); a5 = fmaf(v, bf2f((Q)[5]), a5);        \
        a6 = fmaf(v, bf2f((Q)[6]), a6); a7 = fmaf(v, bf2f((Q)[7]), a7);        \
    } while (0)

#define FMAG(C0, C1, C2, C3, Q0, Q1, Q2, Q3)                                   \
    do {                                                                       \
        EDGE_FMA(C0, Q0); EDGE_FMA(C1, Q1);                                    \
        EDGE_FMA(C2, Q2); EDGE_FMA(C3, Q3);                                    \
    } while (0)

    unsigned int c0, c1, c2, c3, d0, d1, d2, d3;
    usv8 qa0, qa1, qa2, qa3, qb0, qb1, qb2, qb3;

    int idx = s;
    int r = (e - s) >> 2;           // full 4-edge groups
    if (r > 0) {
        LOADG(c0, c1, c2, c3, qa0, qa1, qa2, qa3, idx); idx += 4; r--;
        while (r >= 2) {
            LOADG(d0, d1, d2, d3, qb0, qb1, qb2, qb3, idx); idx += 4;
            FMAG(c0, c1, c2, c3, qa0, qa1, qa2, qa3);
            LOADG(c0, c1, c2, c3, qa0, qa1, qa2, qa3, idx); idx += 4;
            FMAG(d0, d1, d2, d3, qb0, qb1, qb2, qb3);
            r -= 2;
        }
        if (r == 1) {
            LOADG(d0, d1, d2, d3, qb0, qb1, qb2, qb3, idx); idx += 4;
            FMAG(c0, c1, c2, c3, qa0, qa1, qa2, qa3);
            FMAG(d0, d1, d2, d3, qb0, qb1, qb2, qb3);
        } else {
            FMAG(c0, c1, c2, c3, qa0, qa1, qa2, qa3);
        }
    }
    for (; idx < e; idx++) {        // tail (<4 edges)
        unsigned int w = __builtin_nontemporal_load(&cv[idx]);
        usv8 q = *(const usv8*)&S[(long)(w & 0xFFFFu) * 512 + soff];
        EDGE_FMA(w, q);
    }

#undef LOADG
#undef EDGE_FMA
#undef FMAG

    f32x4 b0 = *(const f32x4*)&bias[f8];
    f32x4 b1 = *(const f32x4*)&bias[f8 + 4];
    long o = (long)(lane >> 5) * NNODES * FOUT + (long)node * FOUT + f8;
    f32x4 r0, r1;
    r0[0] = fmaxf(a0 + b0[0], 0.f); r0[1] = fmaxf(a1 + b0[1], 0.f);
    r0[2] = fmaxf(a2 + b0[2], 0.f); r0[3] = fmaxf(a3 + b0[3], 0.f);
    r1[0] = fmaxf(a4 + b1[0], 0.f); r1[1] = fmaxf(a5 + b1[1], 0.f);
    r1[2] = fmaxf(a6 + b1[2], 0.f); r1[3] = fmaxf(a7 + b1[3], 0.f);
    __builtin_nontemporal_store(r0, (f32x4*)&out[o]);
    __builtin_nontemporal_store(r1, (f32x4*)&out[o + 4]);
}

// ---------------- launch ----------------------------------------------------
extern "C" void kernel_launch(void* const* d_in, const int* in_sizes, int n_in,
                              void* d_out, int out_size, void* d_ws, size_t ws_size,
                              hipStream_t stream) {
    const float* Xo   = (const float*)d_in[0];
    const float* Xa   = (const float*)d_in[1];
    const int*   erow = (const int*)d_in[2];
    const int*   ecol = (const int*)d_in[3];
    const float* eval_= (const float*)d_in[4];
    const float* W    = (const float*)d_in[5];
    const float* bias = (const float*)d_in[6];
    float* out = (float*)d_out;

    char* ws = (char*)d_ws;
    // workspace layout (~55.06 MB total)
    unsigned short* S         = (unsigned short*)(ws);                 // 51,200,000 B
    unsigned short* Wt        = (unsigned short*)(ws + 51200000);      //    262,144 B
    int*            cnt       = (int*)(ws + 51462144);                 //    200,000 B (hist, then cursor)
    int*            row_start = (int*)(ws + 51662144);                 //    200,064 B (50001 ints)
    int*            partial   = (int*)(ws + 51862208);                 //      1,024 B
    unsigned int*   cv        = (unsigned int*)(ws + 51863232);        //  3,200,000 B

    (void)in_sizes; (void)n_in; (void)out_size; (void)ws_size;

    hipMemsetAsync(cnt, 0, 200000, stream);
    prep_kernel<<<3637, 256, 0, stream>>>(W, Wt, erow, cnt);
    scan_partial<<<196, 256, 0, stream>>>(cnt, partial);
    scan_exclusive_small<<<1, 256, 0, stream>>>(partial, 196);
    scan_write<<<196, 256, 0, stream>>>(cnt, partial, row_start, cnt);
    scatter_kernel<<<3125, 256, 0, stream>>>(erow, ecol, eval_, cnt, cv);

    dim3 gg(391, 1, 2);
    gemm_kernel<<<gg, 512, 0, stream>>>(Xo, Xa, Wt, S);

    aggregate_kernel<<<12500, 256, 0, stream>>>(row_start, cv, S, bias, out);
}

// Round 3
// 482.479 us; speedup vs baseline: 1.0154x; 1.0094x over previous
//
#include <hip/hip_runtime.h>
#include <hip/hip_bf16.h>

// Problem constants (fixed by reference setup_inputs)
#define NNODES 50000
#define NEDGES 800000
#define DIN    512
#define FOUT   256

typedef __attribute__((ext_vector_type(8))) short short8;
typedef __attribute__((ext_vector_type(4))) float f32x4;
typedef __attribute__((ext_vector_type(4))) unsigned int u32x4;
typedef __attribute__((ext_vector_type(4))) unsigned short usv4;
typedef __attribute__((ext_vector_type(8))) unsigned short usv8;

static __device__ __forceinline__ unsigned short f2bf(float f) {
    unsigned int u = __float_as_uint(f);
    u += 0x7FFF + ((u >> 16) & 1);   // round-to-nearest-even
    return (unsigned short)(u >> 16);
}
static __device__ __forceinline__ float bf2f(unsigned short h) {
    return __uint_as_float(((unsigned int)h) << 16);
}

// ---------------- prep: W^T convert (blocks 0..511) + edge hist (512..) -----
__global__ void prep_kernel(const float* __restrict__ W, unsigned short* __restrict__ Wt,
                            const int* __restrict__ row, int* __restrict__ cnt) {
    int b = blockIdx.x;
    if (b < 512) {
        int o = b * 256 + threadIdx.x;           // 131072 total
        int n = o >> 9, k = o & 511;
        Wt[o] = f2bf(W[k * FOUT + n]);
    } else {
        int e = (b - 512) * 256 + threadIdx.x;
        if (e < NEDGES) atomicAdd(&cnt[row[e]], 1);
    }
}

// ---------------- CSR scan --------------------------------------------------
__global__ void scan_partial(const int* __restrict__ cnt, int* __restrict__ partial) {
    __shared__ int sm[256];
    int i = blockIdx.x * 256 + threadIdx.x;
    int v = (i < NNODES) ? cnt[i] : 0;
    sm[threadIdx.x] = v; __syncthreads();
    for (int s = 128; s > 0; s >>= 1) {
        if (threadIdx.x < s) sm[threadIdx.x] += sm[threadIdx.x + s];
        __syncthreads();
    }
    if (threadIdx.x == 0) partial[blockIdx.x] = sm[0];
}

__global__ void scan_exclusive_small(int* __restrict__ partial, int nb) {
    __shared__ int sm[256];
    int t = threadIdx.x;
    int v = (t < nb) ? partial[t] : 0;
    sm[t] = v; __syncthreads();
    for (int off = 1; off < 256; off <<= 1) {
        int add = (t >= off) ? sm[t - off] : 0;
        __syncthreads();
        sm[t] += add;
        __syncthreads();
    }
    if (t < nb) partial[t] = sm[t] - v;   // exclusive
}

// Writes row_start AND initializes the scatter cursor to the same value
// (cursor aliases cnt: each thread reads cnt[i] first, writes it last — safe).
__global__ void scan_write(const int* __restrict__ cnt, const int* __restrict__ partial,
                           int* __restrict__ row_start, int* __restrict__ cursor) {
    __shared__ int sm[256];
    int t = threadIdx.x;
    int i = blockIdx.x * 256 + t;
    int v = (i < NNODES) ? cnt[i] : 0;
    sm[t] = v; __syncthreads();
    for (int off = 1; off < 256; off <<= 1) {
        int add = (t >= off) ? sm[t - off] : 0;
        __syncthreads();
        sm[t] += add;
        __syncthreads();
    }
    if (i < NNODES) {
        int rs = partial[blockIdx.x] + sm[t] - v;
        row_start[i] = rs;
        cursor[i] = rs;          // absolute cursor for scatter
    }
    if (i == 0) row_start[NNODES] = NEDGES;
}

// scatter: cursor[r] pre-initialized to row_start[r] -> atomicAdd gives the
// absolute CSR slot directly (no row_start read per edge).
__global__ void scatter_kernel(const int* __restrict__ row, const int* __restrict__ col,
                               const float* __restrict__ val,
                               int* __restrict__ cursor, unsigned int* __restrict__ cv) {
    int e = blockIdx.x * 256 + threadIdx.x;
    if (e < NEDGES) {
        int r = row[e];
        int pos = atomicAdd(&cursor[r], 1);
        unsigned int vb = f2bf(val[e]);
        cv[pos] = (vb << 16) | (unsigned int)col[e];
    }
}

// ---------------- GEMM: S[m][512] = [X@W (ori) | X@W (aug)] bf16 ------------
__global__ __launch_bounds__(512, 2)
void gemm_kernel(const float* __restrict__ Xo, const float* __restrict__ Xa,
                 const unsigned short* __restrict__ Wt,
                 unsigned short* __restrict__ S) {
    __shared__ __align__(16) unsigned short As[2][128][40];
    __shared__ __align__(16) unsigned short Bs[2][256][40];
    const int tid = threadIdx.x;
    const int branch = blockIdx.z;
    const float* __restrict__ X = branch ? Xa : Xo;
    const int boff = branch * 256;
    const int m_base = blockIdx.x * 128;
    const int lane = tid & 63, wave = tid >> 6;
    const int wm = (wave >> 2) * 64, wn = (wave & 3) * 64;
    const int quad = lane >> 4, r16 = lane & 15;

    f32x4 acc[4][4] = {};

    const int colf  = (tid & 7) * 4;   // A: float4 column within 32-k tile
    const int rbase = tid >> 3;        // A: row 0..63 (2 passes)
    const int kseg  = (tid & 3) * 8;   // B: 8-bf16 segment
    const int nrow  = tid >> 2;        // B: n row 0..127 (2 passes)

    const int gm0 = m_base + rbase;
    const int gm1 = m_base + 64 + rbase;
    const bool va0 = gm0 < NNODES, va1 = gm1 < NNODES;
    const float* pA0 = &X[(long)gm0 * DIN + colf];
    const float* pA1 = &X[(long)gm1 * DIN + colf];
    const unsigned short* pB0 = &Wt[(long)nrow * DIN + kseg];
    const unsigned short* pB1 = &Wt[(long)(128 + nrow) * DIN + kseg];

    f32x4 fa0, fa1; u32x4 ub0, ub1;

#define GEMM_LOAD(K0)                                                          \
    do {                                                                       \
        fa0 = va0 ? __builtin_nontemporal_load((const f32x4*)(pA0 + (K0)))     \
                  : (f32x4)0.f;                                                \
        fa1 = va1 ? __builtin_nontemporal_load((const f32x4*)(pA1 + (K0)))     \
                  : (f32x4)0.f;                                                \
        ub0 = *(const u32x4*)(pB0 + (K0));                                     \
        ub1 = *(const u32x4*)(pB1 + (K0));                                     \
    } while (0)

#define GEMM_WRITE(B)                                                          \
    do {                                                                       \
        usv4 h0; h0.x = f2bf(fa0[0]); h0.y = f2bf(fa0[1]);                     \
        h0.z = f2bf(fa0[2]); h0.w = f2bf(fa0[3]);                              \
        *(usv4*)&As[B][rbase][colf] = h0;                                      \
        usv4 h1; h1.x = f2bf(fa1[0]); h1.y = f2bf(fa1[1]);                     \
        h1.z = f2bf(fa1[2]); h1.w = f2bf(fa1[3]);                              \
        *(usv4*)&As[B][64 + rbase][colf] = h1;                                 \
        *(u32x4*)&Bs[B][nrow][kseg] = ub0;                                     \
        *(u32x4*)&Bs[B][128 + nrow][kseg] = ub1;                               \
    } while (0)

#define GEMM_COMPUTE(B)                                                        \
    do {                                                                       \
        short8 a_frag[4], b_frag[4];                                           \
        _Pragma("unroll")                                                      \
        for (int mi = 0; mi < 4; mi++)                                         \
            a_frag[mi] = *(const short8*)&As[B][wm + mi * 16 + r16][quad * 8]; \
        _Pragma("unroll")                                                      \
        for (int ni = 0; ni < 4; ni++)                                         \
            b_frag[ni] = *(const short8*)&Bs[B][wn + ni * 16 + r16][quad * 8]; \
        _Pragma("unroll")                                                      \
        for (int mi = 0; mi < 4; mi++)                                         \
            _Pragma("unroll")                                                  \
            for (int ni = 0; ni < 4; ni++)                                     \
                acc[mi][ni] = __builtin_amdgcn_mfma_f32_16x16x32_bf16(         \
                    a_frag[mi], b_frag[ni], acc[mi][ni], 0, 0, 0);             \
    } while (0)

    GEMM_LOAD(0);
    GEMM_WRITE(0);
    __syncthreads();

    for (int k0 = 0; k0 < DIN; k0 += 64) {
        GEMM_LOAD(k0 + 32);
        GEMM_COMPUTE(0);
        GEMM_WRITE(1);
        __syncthreads();
        if (k0 + 64 < DIN) GEMM_LOAD(k0 + 64);
        GEMM_COMPUTE(1);
        if (k0 + 64 < DIN) GEMM_WRITE(0);
        __syncthreads();
    }

#undef GEMM_LOAD
#undef GEMM_WRITE
#undef GEMM_COMPUTE

    // epilogue: bf16 support, interleaved [m][ori 0..255 | aug 256..511]
    // C/D map: col(n)=lane&15, row(m)=quad*4+reg. Plain stores keep S in L2/L3.
    #pragma unroll
    for (int mi = 0; mi < 4; mi++) {
        #pragma unroll
        for (int rr = 0; rr < 4; rr++) {
            int m = m_base + wm + mi * 16 + quad * 4 + rr;
            if (m < NNODES) {
                #pragma unroll
                for (int ni = 0; ni < 4; ni++) {
                    int n = wn + ni * 16 + r16;
                    S[(long)m * 512 + boff + n] = f2bf(acc[mi][ni][rr]);
                }
            }
        }
    }
}

// ---------------- Aggregation: two branch-passes, scalar edge stream --------
// One wave per node. node via readfirstlane -> SGPR: row_start & cv loads go
// through the SCALAR path (lgkmcnt), decoupled from the S-gather vmcnt domain
// -> the 2-deep pipeline's S loads genuinely stay in flight across groups.
// Lanes 0..31 take even edges, 32..63 odd edges; 16B (8 bf16 feats) per lane.
// Per-pass line working set = 25.6 MB (halved) for better L2 hit rate.
__global__ __launch_bounds__(256)
void aggregate_pass(const int* __restrict__ row_start,
                    const unsigned int* __restrict__ cv,
                    const unsigned short* __restrict__ S,
                    const float* __restrict__ bias, float* __restrict__ out,
                    const int half) {
    const int node = __builtin_amdgcn_readfirstlane(blockIdx.x * 4 + (threadIdx.x >> 6));
    if (node >= NNODES) return;
    const int lane = threadIdx.x & 63;
    const int fl = (lane & 31) * 8;                 // feature base 0..248
    const unsigned int sub = lane >> 5;             // 0: even edge, 1: odd edge
    const long soff = (long)half * 256 + fl;
    const int s = row_start[node], e = row_start[node + 1];

    float a0 = 0.f, a1 = 0.f, a2 = 0.f, a3 = 0.f;
    float a4 = 0.f, a5 = 0.f, a6 = 0.f, a7 = 0.f;

#define PLOAD(CW0, CW1, Q)                                                     \
    do {                                                                       \
        unsigned int cw_ = sub ? (CW1) : (CW0);                                \
        Q = *(const usv8*)&S[(long)(cw_ & 0xFFFFu) * 512 + soff];              \
    } while (0)

#define PFMA(CW0, CW1, Q)                                                      \
    do {                                                                       \
        unsigned int cw_ = sub ? (CW1) : (CW0);                                \
        float v = bf2f((unsigned short)(cw_ >> 16));                           \
        a0 = fmaf(v, bf2f((Q)[0]), a0); a1 = fmaf(v, bf2f((Q)[1]), a1);        \
        a2 = fmaf(v, bf2f((Q)[2]), a2); a3 = fmaf(v, bf2f((Q)[3]), a3);        \
        a4 = fmaf(v, bf2f((Q)[4]), a4); a5 = fmaf(v, bf2f((Q)[5]), a5);        \
        a6 = fmaf(v, bf2f((Q)[6]), a6); a7 = fmaf(v, bf2f((Q)[7]), a7);        \
    } while (0)

#define LOADG(C0, C1, C2, C3, C4, C5, C6, C7, Q0, Q1, Q2, Q3, I)               \
    do {                                                                       \
        C0 = cv[(I)];     C1 = cv[(I) + 1]; C2 = cv[(I) + 2]; C3 = cv[(I) + 3];\
        C4 = cv[(I) + 4]; C5 = cv[(I) + 5]; C6 = cv[(I) + 6]; C7 = cv[(I) + 7];\
        PLOAD(C0, C1, Q0); PLOAD(C2, C3, Q1);                                  \
        PLOAD(C4, C5, Q2); PLOAD(C6, C7, Q3);                                  \
    } while (0)

#define FMAG(C0, C1, C2, C3, C4, C5, C6, C7, Q0, Q1, Q2, Q3)                   \
    do {                                                                       \
        PFMA(C0, C1, Q0); PFMA(C2, C3, Q1);                                    \
        PFMA(C4, C5, Q2); PFMA(C6, C7, Q3);                                    \
    } while (0)

    unsigned int c0, c1, c2, c3, c4, c5, c6, c7;
    unsigned int d0, d1, d2, d3, d4, d5, d6, d7;
    usv8 qa0, qa1, qa2, qa3, qb0, qb1, qb2, qb3;

    int idx = s;
    int r = (e - s) >> 3;           // full 8-edge groups
    if (r > 0) {
        LOADG(c0, c1, c2, c3, c4, c5, c6, c7, qa0, qa1, qa2, qa3, idx); idx += 8; r--;
        while (r >= 2) {
            LOADG(d0, d1, d2, d3, d4, d5, d6, d7, qb0, qb1, qb2, qb3, idx); idx += 8;
            FMAG(c0, c1, c2, c3, c4, c5, c6, c7, qa0, qa1, qa2, qa3);
            LOADG(c0, c1, c2, c3, c4, c5, c6, c7, qa0, qa1, qa2, qa3, idx); idx += 8;
            FMAG(d0, d1, d2, d3, d4, d5, d6, d7, qb0, qb1, qb2, qb3);
            r -= 2;
        }
        if (r == 1) {
            LOADG(d0, d1, d2, d3, d4, d5, d6, d7, qb0, qb1, qb2, qb3, idx); idx += 8;
            FMAG(c0, c1, c2, c3, c4, c5, c6, c7, qa0, qa1, qa2, qa3);
            FMAG(d0, d1, d2, d3, d4, d5, d6, d7, qb0, qb1, qb2, qb3);
        } else {
            FMAG(c0, c1, c2, c3, c4, c5, c6, c7, qa0, qa1, qa2, qa3);
        }
    }
    // pair tail
    for (; idx + 2 <= e; idx += 2) {
        unsigned int w0 = cv[idx], w1 = cv[idx + 1];
        usv8 q;
        PLOAD(w0, w1, q);
        PFMA(w0, w1, q);
    }
    // final odd edge: only the even half-wave contributes
    if (idx < e) {
        unsigned int w = cv[idx];
        usv8 q = *(const usv8*)&S[(long)(w & 0xFFFFu) * 512 + soff];
        float v = sub ? 0.f : bf2f((unsigned short)(w >> 16));
        a0 = fmaf(v, bf2f(q[0]), a0); a1 = fmaf(v, bf2f(q[1]), a1);
        a2 = fmaf(v, bf2f(q[2]), a2); a3 = fmaf(v, bf2f(q[3]), a3);
        a4 = fmaf(v, bf2f(q[4]), a4); a5 = fmaf(v, bf2f(q[5]), a5);
        a6 = fmaf(v, bf2f(q[6]), a6); a7 = fmaf(v, bf2f(q[7]), a7);
    }

#undef PLOAD
#undef PFMA
#undef LOADG
#undef FMAG

    // combine even/odd halves: lane l += lane l^32
    a0 += __shfl_xor(a0, 32); a1 += __shfl_xor(a1, 32);
    a2 += __shfl_xor(a2, 32); a3 += __shfl_xor(a3, 32);
    a4 += __shfl_xor(a4, 32); a5 += __shfl_xor(a5, 32);
    a6 += __shfl_xor(a6, 32); a7 += __shfl_xor(a7, 32);

    if (lane < 32) {
        f32x4 b0 = *(const f32x4*)&bias[fl];
        f32x4 b1 = *(const f32x4*)&bias[fl + 4];
        long o = (long)half * NNODES * FOUT + (long)node * FOUT + fl;
        f32x4 r0, r1;
        r0[0] = fmaxf(a0 + b0[0], 0.f); r0[1] = fmaxf(a1 + b0[1], 0.f);
        r0[2] = fmaxf(a2 + b0[2], 0.f); r0[3] = fmaxf(a3 + b0[3], 0.f);
        r1[0] = fmaxf(a4 + b1[0], 0.f); r1[1] = fmaxf(a5 + b1[1], 0.f);
        r1[2] = fmaxf(a6 + b1[2], 0.f); r1[3] = fmaxf(a7 + b1[3], 0.f);
        __builtin_nontemporal_store(r0, (f32x4*)&out[o]);
        __builtin_nontemporal_store(r1, (f32x4*)&out[o + 4]);
    }
}

// ---------------- launch ----------------------------------------------------
extern "C" void kernel_launch(void* const* d_in, const int* in_sizes, int n_in,
                              void* d_out, int out_size, void* d_ws, size_t ws_size,
                              hipStream_t stream) {
    const float* Xo   = (const float*)d_in[0];
    const float* Xa   = (const float*)d_in[1];
    const int*   erow = (const int*)d_in[2];
    const int*   ecol = (const int*)d_in[3];
    const float* eval_= (const float*)d_in[4];
    const float* W    = (const float*)d_in[5];
    const float* bias = (const float*)d_in[6];
    float* out = (float*)d_out;

    char* ws = (char*)d_ws;
    // workspace layout (~55.06 MB total)
    unsigned short* S         = (unsigned short*)(ws);                 // 51,200,000 B
    unsigned short* Wt        = (unsigned short*)(ws + 51200000);      //    262,144 B
    int*            cnt       = (int*)(ws + 51462144);                 //    200,000 B (hist, then cursor)
    int*            row_start = (int*)(ws + 51662144);                 //    200,064 B (50001 ints)
    int*            partial   = (int*)(ws + 51862208);                 //      1,024 B
    unsigned int*   cv        = (unsigned int*)(ws + 51863232);        //  3,200,000 B

    (void)in_sizes; (void)n_in; (void)out_size; (void)ws_size;

    hipMemsetAsync(cnt, 0, 200000, stream);
    prep_kernel<<<3637, 256, 0, stream>>>(W, Wt, erow, cnt);
    scan_partial<<<196, 256, 0, stream>>>(cnt, partial);
    scan_exclusive_small<<<1, 256, 0, stream>>>(partial, 196);
    scan_write<<<196, 256, 0, stream>>>(cnt, partial, row_start, cnt);
    scatter_kernel<<<3125, 256, 0, stream>>>(erow, ecol, eval_, cnt, cv);

    dim3 gg(391, 1, 2);
    gemm_kernel<<<gg, 512, 0, stream>>>(Xo, Xa, Wt, S);

    aggregate_pass<<<12500, 256, 0, stream>>>(row_start, cv, S, bias, out, 0);
    aggregate_pass<<<12500, 256, 0, stream>>>(row_start, cv, S, bias, out, 1);
}

// Round 4
// 469.086 us; speedup vs baseline: 1.0444x; 1.0286x over previous
//
#include <hip/hip_runtime.h>
#include <hip/hip_bf16.h>

// Problem constants (fixed by reference setup_inputs)
#define NNODES 50000
#define NEDGES 800000
#define DIN    512
#define FOUT   256

typedef __attribute__((ext_vector_type(8))) short short8;
typedef __attribute__((ext_vector_type(4))) float f32x4;
typedef __attribute__((ext_vector_type(4))) unsigned int u32x4;
typedef __attribute__((ext_vector_type(4))) unsigned short usv4;
typedef __attribute__((ext_vector_type(8))) unsigned short usv8;

static __device__ __forceinline__ unsigned short f2bf(float f) {
    unsigned int u = __float_as_uint(f);
    u += 0x7FFF + ((u >> 16) & 1);   // round-to-nearest-even
    return (unsigned short)(u >> 16);
}
static __device__ __forceinline__ float bf2f(unsigned short h) {
    return __uint_as_float(((unsigned int)h) << 16);
}

// ---------------- prep: W^T convert (blocks 0..511) + edge hist (512..) -----
__global__ void prep_kernel(const float* __restrict__ W, unsigned short* __restrict__ Wt,
                            const int* __restrict__ row, int* __restrict__ cnt) {
    int b = blockIdx.x;
    if (b < 512) {
        int o = b * 256 + threadIdx.x;           // 131072 total
        int n = o >> 9, k = o & 511;
        Wt[o] = f2bf(W[k * FOUT + n]);
    } else {
        int e = (b - 512) * 256 + threadIdx.x;
        if (e < NEDGES) atomicAdd(&cnt[row[e]], 1);
    }
}

// ---------------- CSR scan --------------------------------------------------
__global__ void scan_partial(const int* __restrict__ cnt, int* __restrict__ partial) {
    __shared__ int sm[256];
    int i = blockIdx.x * 256 + threadIdx.x;
    int v = (i < NNODES) ? cnt[i] : 0;
    sm[threadIdx.x] = v; __syncthreads();
    for (int s = 128; s > 0; s >>= 1) {
        if (threadIdx.x < s) sm[threadIdx.x] += sm[threadIdx.x + s];
        __syncthreads();
    }
    if (threadIdx.x == 0) partial[blockIdx.x] = sm[0];
}

__global__ void scan_exclusive_small(int* __restrict__ partial, int nb) {
    __shared__ int sm[256];
    int t = threadIdx.x;
    int v = (t < nb) ? partial[t] : 0;
    sm[t] = v; __syncthreads();
    for (int off = 1; off < 256; off <<= 1) {
        int add = (t >= off) ? sm[t - off] : 0;
        __syncthreads();
        sm[t] += add;
        __syncthreads();
    }
    if (t < nb) partial[t] = sm[t] - v;   // exclusive
}

// Writes row_start AND initializes the scatter cursor to the same value.
__global__ void scan_write(const int* __restrict__ cnt, const int* __restrict__ partial,
                           int* __restrict__ row_start, int* __restrict__ cursor) {
    __shared__ int sm[256];
    int t = threadIdx.x;
    int i = blockIdx.x * 256 + t;
    int v = (i < NNODES) ? cnt[i] : 0;
    sm[t] = v; __syncthreads();
    for (int off = 1; off < 256; off <<= 1) {
        int add = (t >= off) ? sm[t - off] : 0;
        __syncthreads();
        sm[t] += add;
        __syncthreads();
    }
    if (i < NNODES) {
        int rs = partial[blockIdx.x] + sm[t] - v;
        row_start[i] = rs;
        cursor[i] = rs;          // absolute cursor for scatter
    }
    if (i == 0) row_start[NNODES] = NEDGES;
}

// scatter: cursor pre-initialized to row_start -> atomicAdd gives CSR slot.
__global__ void scatter_kernel(const int* __restrict__ row, const int* __restrict__ col,
                               const float* __restrict__ val,
                               int* __restrict__ cursor, unsigned int* __restrict__ cv) {
    int e = blockIdx.x * 256 + threadIdx.x;
    if (e < NEDGES) {
        int r = row[e];
        int pos = atomicAdd(&cursor[r], 1);
        unsigned int vb = f2bf(val[e]);
        cv[pos] = (vb << 16) | (unsigned int)col[e];
    }
}

// ---------------- GEMM: S[m][512] = [X@W (ori) | X@W (aug)] bf16 ------------
// 128(m) x 256(n) block, BK=32, 8 waves of 64x64. Distance-2 register
// prefetch (static A/B sets), raw s_barrier with lgkmcnt-only drain: global
// loads stay in flight ACROSS barriers (T4); compiler emits counted vmcnt at
// the consuming cvt. One barrier per K-step. A staged in one pass: 32B f32
// load -> 16B bf16 ds_write_b128.
__global__ __launch_bounds__(512, 2)
void gemm_kernel(const float* __restrict__ Xo, const float* __restrict__ Xa,
                 const unsigned short* __restrict__ Wt,
                 unsigned short* __restrict__ S) {
    __shared__ __align__(16) unsigned short As[2][128][40];
    __shared__ __align__(16) unsigned short Bs[2][256][40];
    const int tid = threadIdx.x;
    const int branch = blockIdx.z;
    const float* __restrict__ X = branch ? Xa : Xo;
    const int boff = branch * 256;
    const int m_base = blockIdx.x * 128;
    const int lane = tid & 63, wave = tid >> 6;
    const int wm = (wave >> 2) * 64, wn = (wave & 3) * 64;
    const int quad = lane >> 4, r16 = lane & 15;

    f32x4 acc[4][4] = {};

    // staging geometry (512 threads, single pass each)
    const int arow = tid >> 2;          // A row 0..127
    const int acol = (tid & 3) * 8;     // A k-offset 0,8,16,24
    const int kseg = (tid & 3) * 8;     // B k-segment
    const int nrow = tid >> 2;          // B n-row 0..127 (+128 second ptr)

    const int gm = m_base + arow;
    const bool va = gm < NNODES;
    const float* pA = &X[(long)gm * DIN + acol];
    const unsigned short* pB0 = &Wt[(long)nrow * DIN + kseg];
    const unsigned short* pB1 = &Wt[(long)(128 + nrow) * DIN + kseg];

    // two static prefetch register sets (rule #20: no runtime indexing)
    f32x4 fa0A, fa1A, fa0B, fa1B;
    u32x4 ub0A, ub1A, ub0B, ub1B;

#define GEMM_LOAD(SET, K0)                                                     \
    do {                                                                       \
        fa0##SET = va ? __builtin_nontemporal_load((const f32x4*)(pA + (K0)))  \
                      : (f32x4)0.f;                                            \
        fa1##SET = va ? __builtin_nontemporal_load((const f32x4*)(pA + (K0) + 4))\
                      : (f32x4)0.f;                                            \
        ub0##SET = *(const u32x4*)(pB0 + (K0));                                \
        ub1##SET = *(const u32x4*)(pB1 + (K0));                                \
    } while (0)

#define GEMM_WRITE(SET, B)                                                     \
    do {                                                                       \
        usv8 h;                                                                \
        h[0] = f2bf(fa0##SET[0]); h[1] = f2bf(fa0##SET[1]);                    \
        h[2] = f2bf(fa0##SET[2]); h[3] = f2bf(fa0##SET[3]);                    \
        h[4] = f2bf(fa1##SET[0]); h[5] = f2bf(fa1##SET[1]);                    \
        h[6] = f2bf(fa1##SET[2]); h[7] = f2bf(fa1##SET[3]);                    \
        *(usv8*)&As[B][arow][acol] = h;                                        \
        *(u32x4*)&Bs[B][nrow][kseg] = ub0##SET;                                \
        *(u32x4*)&Bs[B][128 + nrow][kseg] = ub1##SET;                          \
    } while (0)

#define GEMM_COMPUTE(B)                                                        \
    do {                                                                       \
        short8 a_frag[4], b_frag[4];                                           \
        _Pragma("unroll")                                                      \
        for (int mi = 0; mi < 4; mi++)                                         \
            a_frag[mi] = *(const short8*)&As[B][wm + mi * 16 + r16][quad * 8]; \
        _Pragma("unroll")                                                      \
        for (int ni = 0; ni < 4; ni++)                                         \
            b_frag[ni] = *(const short8*)&Bs[B][wn + ni * 16 + r16][quad * 8]; \
        _Pragma("unroll")                                                      \
        for (int mi = 0; mi < 4; mi++)                                         \
            _Pragma("unroll")                                                  \
            for (int ni = 0; ni < 4; ni++)                                     \
                acc[mi][ni] = __builtin_amdgcn_mfma_f32_16x16x32_bf16(         \
                    a_frag[mi], b_frag[ni], acc[mi][ni], 0, 0, 0);             \
    } while (0)

// lgkmcnt-only drain before barrier: ds_writes must be visible, but global
// loads into private VGPRs may stay in flight (T4). sched_barrier(0) fences
// against hoisting next-step LDS ops above the barrier (rule #18).
#define GEMM_BARRIER()                                                         \
    do {                                                                       \
        asm volatile("s_waitcnt lgkmcnt(0)" ::: "memory");                     \
        __builtin_amdgcn_s_barrier();                                          \
        __builtin_amdgcn_sched_barrier(0);                                     \
    } while (0)

    // prologue: tile0 -> buf0; tile1 loads in flight in set A
    GEMM_LOAD(A, 0);
    GEMM_WRITE(A, 0);
    GEMM_LOAD(A, 32);
    GEMM_BARRIER();

    // steady state invariant (top of even step t): buf0 = tile t,
    // set A = tile t+1 (in flight). 16 tiles of BK=32.
    #pragma unroll
    for (int t = 0; t < 16; t += 2) {
        if (t + 2 < 16) GEMM_LOAD(B, (t + 2) * 32);   // dist-2 prefetch
        GEMM_COMPUTE(0);
        GEMM_WRITE(A, 1);
        GEMM_BARRIER();
        if (t + 3 < 16) GEMM_LOAD(A, (t + 3) * 32);
        GEMM_COMPUTE(1);
        if (t + 2 < 16) {
            GEMM_WRITE(B, 0);
            GEMM_BARRIER();
        }
    }

#undef GEMM_LOAD
#undef GEMM_WRITE
#undef GEMM_COMPUTE
#undef GEMM_BARRIER

    // epilogue: bf16 support, interleaved [m][ori 0..255 | aug 256..511]
    // C/D map: col(n)=lane&15, row(m)=quad*4+reg. Plain stores keep S in L2/L3.
    #pragma unroll
    for (int mi = 0; mi < 4; mi++) {
        #pragma unroll
        for (int rr = 0; rr < 4; rr++) {
            int m = m_base + wm + mi * 16 + quad * 4 + rr;
            if (m < NNODES) {
                #pragma unroll
                for (int ni = 0; ni < 4; ni++) {
                    int n = wn + ni * 16 + r16;
                    S[(long)m * 512 + boff + n] = f2bf(acc[mi][ni][rr]);
                }
            }
        }
    }
}

// ---------------- Aggregation: two branch-passes, scalar edge stream --------
__global__ __launch_bounds__(256)
void aggregate_pass(const int* __restrict__ row_start,
                    const unsigned int* __restrict__ cv,
                    const unsigned short* __restrict__ S,
                    const float* __restrict__ bias, float* __restrict__ out,
                    const int half) {
    const int node = __builtin_amdgcn_readfirstlane(blockIdx.x * 4 + (threadIdx.x >> 6));
    if (node >= NNODES) return;
    const int lane = threadIdx.x & 63;
    const int fl = (lane & 31) * 8;                 // feature base 0..248
    const unsigned int sub = lane >> 5;             // 0: even edge, 1: odd edge
    const long soff = (long)half * 256 + fl;
    const int s = row_start[node], e = row_start[node + 1];

    float a0 = 0.f, a1 = 0.f, a2 = 0.f, a3 = 0.f;
    float a4 = 0.f, a5 = 0.f, a6 = 0.f, a7 = 0.f;

#define PLOAD(CW0, CW1, Q)                                                     \
    do {                                                                       \
        unsigned int cw_ = sub ? (CW1) : (CW0);                                \
        Q = *(const usv8*)&S[(long)(cw_ & 0xFFFFu) * 512 + soff];              \
    } while (0)

#define PFMA(CW0, CW1, Q)                                                      \
    do {                                                                       \
        unsigned int cw_ = sub ? (CW1) : (CW0);                                \
        float v = bf2f((unsigned short)(cw_ >> 16));                           \
        a0 = fmaf(v, bf2f((Q)[0]), a0); a1 = fmaf(v, bf2f((Q)[1]), a1);        \
        a2 = fmaf(v, bf2f((Q)[2]), a2); a3 = fmaf(v, bf2f((Q)[3]), a3);        \
        a4 = fmaf(v, bf2f((Q)[4]), a4); a5 = fmaf(v, bf2f((Q)[5]), a5);        \
        a6 = fmaf(v, bf2f((Q)[6]), a6); a7 = fmaf(v, bf2f((Q)[7]), a7);        \
    } while (0)

#define LOADG(C0, C1, C2, C3, C4, C5, C6, C7, Q0, Q1, Q2, Q3, I)               \
    do {                                                                       \
        C0 = cv[(I)];     C1 = cv[(I) + 1]; C2 = cv[(I) + 2]; C3 = cv[(I) + 3];\
        C4 = cv[(I) + 4]; C5 = cv[(I) + 5]; C6 = cv[(I) + 6]; C7 = cv[(I) + 7];\
        PLOAD(C0, C1, Q0); PLOAD(C2, C3, Q1);                                  \
        PLOAD(C4, C5, Q2); PLOAD(C6, C7, Q3);                                  \
    } while (0)

#define FMAG(C0, C1, C2, C3, C4, C5, C6, C7, Q0, Q1, Q2, Q3)                   \
    do {                                                                       \
        PFMA(C0, C1, Q0); PFMA(C2, C3, Q1);                                    \
        PFMA(C4, C5, Q2); PFMA(C6, C7, Q3);                                    \
    } while (0)

    unsigned int c0, c1, c2, c3, c4, c5, c6, c7;
    unsigned int d0, d1, d2, d3, d4, d5, d6, d7;
    usv8 qa0, qa1, qa2, qa3, qb0, qb1, qb2, qb3;

    int idx = s;
    int r = (e - s) >> 3;           // full 8-edge groups
    if (r > 0) {
        LOADG(c0, c1, c2, c3, c4, c5, c6, c7, qa0, qa1, qa2, qa3, idx); idx += 8; r--;
        while (r >= 2) {
            LOADG(d0, d1, d2, d3, d4, d5, d6, d7, qb0, qb1, qb2, qb3, idx); idx += 8;
            FMAG(c0, c1, c2, c3, c4, c5, c6, c7, qa0, qa1, qa2, qa3);
            LOADG(c0, c1, c2, c3, c4, c5, c6, c7, qa0, qa1, qa2, qa3, idx); idx += 8;
            FMAG(d0, d1, d2, d3, d4, d5, d6, d7, qb0, qb1, qb2, qb3);
            r -= 2;
        }
        if (r == 1) {
            LOADG(d0, d1, d2, d3, d4, d5, d6, d7, qb0, qb1, qb2, qb3, idx); idx += 8;
            FMAG(c0, c1, c2, c3, c4, c5, c6, c7, qa0, qa1, qa2, qa3);
            FMAG(d0, d1, d2, d3, d4, d5, d6, d7, qb0, qb1, qb2, qb3);
        } else {
            FMAG(c0, c1, c2, c3, c4, c5, c6, c7, qa0, qa1, qa2, qa3);
        }
    }
    // pair tail
    for (; idx + 2 <= e; idx += 2) {
        unsigned int w0 = cv[idx], w1 = cv[idx + 1];
        usv8 q;
        PLOAD(w0, w1, q);
        PFMA(w0, w1, q);
    }
    // final odd edge: only the even half-wave contributes
    if (idx < e) {
        unsigned int w = cv[idx];
        usv8 q = *(const usv8*)&S[(long)(w & 0xFFFFu) * 512 + soff];
        float v = sub ? 0.f : bf2f((unsigned short)(w >> 16));
        a0 = fmaf(v, bf2f(q[0]), a0); a1 = fmaf(v, bf2f(q[1]), a1);
        a2 = fmaf(v, bf2f(q[2]), a2); a3 = fmaf(v, bf2f(q[3]), a3);
        a4 = fmaf(v, bf2f(q[4]), a4); a5 = fmaf(v, bf2f(q[5]), a5);
        a6 = fmaf(v, bf2f(q[6]), a6); a7 = fmaf(v, bf2f(q[7]), a7);
    }

#undef PLOAD
#undef PFMA
#undef LOADG
#undef FMAG

    // combine even/odd halves: lane l += lane l^32
    a0 += __shfl_xor(a0, 32); a1 += __shfl_xor(a1, 32);
    a2 += __shfl_xor(a2, 32); a3 += __shfl_xor(a3, 32);
    a4 += __shfl_xor(a4, 32); a5 += __shfl_xor(a5, 32);
    a6 += __shfl_xor(a6, 32); a7 += __shfl_xor(a7, 32);

    if (lane < 32) {
        f32x4 b0 = *(const f32x4*)&bias[fl];
        f32x4 b1 = *(const f32x4*)&bias[fl + 4];
        long o = (long)half * NNODES * FOUT + (long)node * FOUT + fl;
        f32x4 r0, r1;
        r0[0] = fmaxf(a0 + b0[0], 0.f); r0[1] = fmaxf(a1 + b0[1], 0.f);
        r0[2] = fmaxf(a2 + b0[2], 0.f); r0[3] = fmaxf(a3 + b0[3], 0.f);
        r1[0] = fmaxf(a4 + b1[0], 0.f); r1[1] = fmaxf(a5 + b1[1], 0.f);
        r1[2] = fmaxf(a6 + b1[2], 0.f); r1[3] = fmaxf(a7 + b1[3], 0.f);
        __builtin_nontemporal_store(r0, (f32x4*)&out[o]);
        __builtin_nontemporal_store(r1, (f32x4*)&out[o + 4]);
    }
}

// ---------------- launch ----------------------------------------------------
extern "C" void kernel_launch(void* const* d_in, const int* in_sizes, int n_in,
                              void* d_out, int out_size, void* d_ws, size_t ws_size,
                              hipStream_t stream) {
    const float* Xo   = (const float*)d_in[0];
    const float* Xa   = (const float*)d_in[1];
    const int*   erow = (const int*)d_in[2];
    const int*   ecol = (const int*)d_in[3];
    const float* eval_= (const float*)d_in[4];
    const float* W    = (const float*)d_in[5];
    const float* bias = (const float*)d_in[6];
    float* out = (float*)d_out;

    char* ws = (char*)d_ws;
    // workspace layout (~55.06 MB total)
    unsigned short* S         = (unsigned short*)(ws);                 // 51,200,000 B
    unsigned short* Wt        = (unsigned short*)(ws + 51200000);      //    262,144 B
    int*            cnt       = (int*)(ws + 51462144);                 //    200,000 B (hist, then cursor)
    int*            row_start = (int*)(ws + 51662144);                 //    200,064 B (50001 ints)
    int*            partial   = (int*)(ws + 51862208);                 //      1,024 B
    unsigned int*   cv        = (unsigned int*)(ws + 51863232);        //  3,200,000 B

    (void)in_sizes; (void)n_in; (void)out_size; (void)ws_size;

    hipMemsetAsync(cnt, 0, 200000, stream);
    prep_kernel<<<3637, 256, 0, stream>>>(W, Wt, erow, cnt);
    scan_partial<<<196, 256, 0, stream>>>(cnt, partial);
    scan_exclusive_small<<<1, 256, 0, stream>>>(partial, 196);
    scan_write<<<196, 256, 0, stream>>>(cnt, partial, row_start, cnt);
    scatter_kernel<<<3125, 256, 0, stream>>>(erow, ecol, eval_, cnt, cv);

    dim3 gg(391, 1, 2);
    gemm_kernel<<<gg, 512, 0, stream>>>(Xo, Xa, Wt, S);

    aggregate_pass<<<12500, 256, 0, stream>>>(row_start, cv, S, bias, out, 0);
    aggregate_pass<<<12500, 256, 0, stream>>>(row_start, cv, S, bias, out, 1);
}